// Round 4
// baseline (78.574 us; speedup 1.0000x reference)
//
#include <hip/hip_runtime.h>
#include <stdint.h>

#define DIM 256
#define NR 8192
#define BM 128
#define BN 128
#define BK 64
#define TPB 8           // tiles per block
#define GRID 512        // 64 bx * 8 bb

typedef __bf16 bf16x8 __attribute__((ext_vector_type(8)));
typedef float  f32x16 __attribute__((ext_vector_type(16)));
typedef float  f32x4  __attribute__((ext_vector_type(4)));

#define MEMFENCE asm volatile("" ::: "memory")
#define WAITV(N) asm volatile("s_waitcnt vmcnt(" #N ")" ::: "memory")
#define BAR __builtin_amdgcn_s_barrier()

__device__ __forceinline__ unsigned short f2bf_rne(float f) {
    unsigned int u = __float_as_uint(f);
    u += 0x7FFFu + ((u >> 16) & 1u);
    return (unsigned short)(u >> 16);
}

// One wave per row: f32 row -> bf16 + ||row||^2. Blocks [0,2048)->a, rest->b.
__global__ void prep_kernel(const float* __restrict__ a,
                            const float* __restrict__ b,
                            unsigned short* __restrict__ aB,
                            unsigned short* __restrict__ bB,
                            float* __restrict__ na,
                            float* __restrict__ nb) {
    const int w = threadIdx.x >> 6;
    const int l = threadIdx.x & 63;
    const int blk = blockIdx.x;
    const float* src; unsigned short* dst; float* nrm; int row;
    if (blk < 2048) { src = a; dst = aB; nrm = na; row = blk * 4 + w; }
    else            { src = b; dst = bB; nrm = nb; row = (blk - 2048) * 4 + w; }
    const float4 v = reinterpret_cast<const float4*>(src + (size_t)row * DIM)[l];
    float ss = v.x * v.x + v.y * v.y + v.z * v.z + v.w * v.w;
#pragma unroll
    for (int off = 32; off > 0; off >>= 1) ss += __shfl_down(ss, off);
    if (l == 0) nrm[row] = ss;
    ushort4 o = make_ushort4(f2bf_rne(v.x), f2bf_rne(v.y), f2bf_rne(v.z), f2bf_rne(v.w));
    reinterpret_cast<ushort4*>(dst + (size_t)row * DIM)[l] = o;
}

// Swizzled staging: LDS granule G=(rp*16+pos) holds global granule
// (r = 2*rp + (c2>>3), c = c2&7) with c2 = pos ^ (rp&15).  Inverse of the
// read mapping byte = ((r>>1)*16 + (((r&1)*8 + c) ^ ((r>>1)&15))) * 16.
#define STAGE(row0_, kt_, buf_)                                                   \
    do {                                                                          \
        _Pragma("unroll")                                                         \
        for (int it_ = 0; it_ < 4; ++it_) {                                       \
            __builtin_amdgcn_global_load_lds(                                     \
                (const __attribute__((address_space(1))) void*)(aB +              \
                    (size_t)((row0_) + rowIt[it_]) * DIM + (kt_) * BK + colIt[it_]), \
                (__attribute__((address_space(3))) void*)&sA[buf_][(w * 4 + it_) * 512], \
                16, 0, 0);                                                        \
        }                                                                         \
        _Pragma("unroll")                                                         \
        for (int it_ = 0; it_ < 4; ++it_) {                                       \
            __builtin_amdgcn_global_load_lds(                                     \
                (const __attribute__((address_space(1))) void*)(bB +              \
                    (size_t)(col0 + rowIt[it_]) * DIM + (kt_) * BK + colIt[it_]), \
                (__attribute__((address_space(3))) void*)&sB[buf_][(w * 4 + it_) * 512], \
                16, 0, 0);                                                        \
        }                                                                         \
    } while (0)

#define COMPUTE(buf_)                                                             \
    do {                                                                          \
        __builtin_amdgcn_s_setprio(1);                                            \
        _Pragma("unroll")                                                         \
        for (int ks_ = 0; ks_ < 4; ++ks_) {                                       \
            bf16x8 af[2], bfv[2];                                                 \
            _Pragma("unroll")                                                     \
            for (int mi_ = 0; mi_ < 2; ++mi_)                                     \
                af[mi_] = *(const bf16x8*)((const char*)&sA[buf_][0] +            \
                    baseA[mi_] + ((XA[mi_] ^ (ks_ << 1)) << 4));                  \
            _Pragma("unroll")                                                     \
            for (int ni_ = 0; ni_ < 2; ++ni_)                                     \
                bfv[ni_] = *(const bf16x8*)((const char*)&sB[buf_][0] +           \
                    baseB[ni_] + ((XB[ni_] ^ (ks_ << 1)) << 4));                  \
            _Pragma("unroll")                                                     \
            for (int mi_ = 0; mi_ < 2; ++mi_)                                     \
                _Pragma("unroll")                                                 \
                for (int ni_ = 0; ni_ < 2; ++ni_)                                 \
                    acc[mi_][ni_] = __builtin_amdgcn_mfma_f32_32x32x16_bf16(      \
                        af[mi_], bfv[ni_], acc[mi_][ni_], 0, 0, 0);               \
        }                                                                         \
        __builtin_amdgcn_s_setprio(0);                                            \
    } while (0)

// Store one 16-value chunk (mi,ni) of outB for the tile whose row base is base_.
#define STORE_CHUNK(c_, base_)                                                    \
    do {                                                                          \
        const int mi_ = (c_) >> 1, ni_ = (c_) & 1;                                \
        const int prow_ = (base_) + wr * 64 + mi_ * 32 + 4 * hi;                  \
        const int pcol_ = col0 + wc * 64 + ni_ * 32 + lr;                         \
        _Pragma("unroll")                                                         \
        for (int tt_ = 0; tt_ < 16; ++tt_) {                                      \
            const int q_ = tt_ & 3, p_ = tt_ >> 2;                                \
            __builtin_nontemporal_store(outB[c_][tt_],                            \
                &out[(size_t)(prow_ + 8 * p_ + q_) * 8192 + pcol_]);              \
        }                                                                         \
    } while (0)

__global__ __launch_bounds__(256, 2) void gemm_kernel(
        const unsigned short* __restrict__ aB,
        const unsigned short* __restrict__ bB,
        const float* __restrict__ na,
        const float* __restrict__ nb,
        float* __restrict__ out) {
    __shared__ unsigned short sA[2][8192];
    __shared__ unsigned short sB[2][8192];
    __shared__ float sNA[1024];      // 8 tiles x 128 row-norms

    const int t = threadIdx.x;
    const int w = t >> 6, l = t & 63;
    const int wr = w >> 1, wc = w & 1;
    const int hi = l >> 5, lr = l & 31;

    const int bx = (int)blockIdx.x & 63;
    const int bb = (int)blockIdx.x >> 6;
    const int col0 = bx * BN;

    // staging source pre-swizzle (constant per thread)
    int rowIt[4], colIt[4];
#pragma unroll
    for (int it = 0; it < 4; ++it) {
        int G = (w * 4 + it) * 64 + l;
        int rp = G >> 4, pos = G & 15;
        int c2 = pos ^ (rp & 15);
        rowIt[it] = 2 * rp + (c2 >> 3);
        colIt[it] = (c2 & 7) * 8;          // ushort offset
    }
    // fragment read bases (byte offsets within 16KB buffer)
    int baseA[2], XA[2], baseB[2], XB[2];
#pragma unroll
    for (int mi = 0; mi < 2; ++mi) {
        int r = wr * 64 + mi * 32 + lr;
        baseA[mi] = (r >> 1) * 256;
        XA[mi] = (((r & 1) * 8) | hi) ^ ((r >> 1) & 15);
        int rb = wc * 64 + mi * 32 + lr;
        baseB[mi] = (rb >> 1) * 256;
        XB[mi] = (((rb & 1) * 8) | hi) ^ ((rb >> 1) & 15);
    }

    float nbv[2];
#pragma unroll
    for (int ni = 0; ni < 2; ++ni) nbv[ni] = nb[col0 + wc * 64 + ni * 32 + lr];

    float outB[4][16];

    // prologue: gather na slices (one f32x4 per thread), stage tile0 k0,k1
    const f32x4 naIn = *(const f32x4*)&na[(bb + (t >> 5) * 8) * 128 + (t & 31) * 4];
    {
        const int r0 = bb * BM;
        STAGE(r0, 0, 0);
        STAGE(r0, 1, 1);
    }
    // compiler inserts the exact vmcnt wait for naIn before this LDS write
    *(f32x4*)&sNA[(t >> 5) * 128 + (t & 31) * 4] = naIn;
    asm volatile("s_waitcnt lgkmcnt(0)" ::: "memory");
    MEMFENCE;

    for (int ti = 0; ti < TPB; ++ti) {
        const int row0 = (bb + ti * 8) * BM;
        f32x16 acc[2][2];
#pragma unroll
        for (int mi = 0; mi < 2; ++mi)
#pragma unroll
            for (int ni = 0; ni < 2; ++ni) acc[mi][ni] = (f32x16)0.0f;

        // ---- P0: compute k0 (buf0, staged at prev tile's P2) ----
        if (ti <= 1) { WAITV(8); } else { WAITV(40); }
        BAR; MEMFENCE;
        COMPUTE(0);
        MEMFENCE; BAR; MEMFENCE;
        STAGE(row0, 2, 0);
        MEMFENCE;
        if (ti > 0) STORE_CHUNK(0, row0 - 1024);
        MEMFENCE;

        // ---- P1: compute k1 (buf1, staged at prev tile's P3) ----
        if (ti == 0) { WAITV(8); } else if (ti == 1) { WAITV(24); } else { WAITV(40); }
        BAR; MEMFENCE;
        COMPUTE(1);
        MEMFENCE; BAR; MEMFENCE;
        STAGE(row0, 3, 1);
        MEMFENCE;
        if (ti > 0) STORE_CHUNK(1, row0 - 1024);
        MEMFENCE;

        // ---- P2: compute k2 (buf0, staged at P0) ----
        if (ti == 0) { WAITV(8); } else { WAITV(40); }
        BAR; MEMFENCE;
        COMPUTE(0);
        MEMFENCE; BAR; MEMFENCE;
        if (ti < TPB - 1) STAGE(row0 + 1024, 0, 0);
        MEMFENCE;
        if (ti > 0) STORE_CHUNK(2, row0 - 1024);
        MEMFENCE;

        // ---- P3: compute k3 (buf1, staged at P1) ----
        if (ti == 0) { WAITV(8); } else if (ti == TPB - 1) { WAITV(32); } else { WAITV(40); }
        BAR; MEMFENCE;
        COMPUTE(1);
        MEMFENCE; BAR; MEMFENCE;
        if (ti < TPB - 1) STAGE(row0 + 1024, 1, 1);
        MEMFENCE;
        if (ti > 0) STORE_CHUNK(3, row0 - 1024);
        MEMFENCE;

        // ---- E: epilogue into outB (no global stores here) ----
#pragma unroll
        for (int mi = 0; mi < 2; ++mi)
#pragma unroll
            for (int ni = 0; ni < 2; ++ni)
#pragma unroll
                for (int p = 0; p < 4; ++p) {
                    const f32x4 nv = *(const f32x4*)&sNA[ti * 128 + wr * 64 + mi * 32 + 8 * p + 4 * hi];
#pragma unroll
                    for (int q = 0; q < 4; ++q) {
                        const float dot = acc[mi][ni][p * 4 + q];
                        const float sq = nv[q] + nbv[ni] - 2.0f * dot;
                        outB[mi * 2 + ni][p * 4 + q] = 0.5f * __expf(-sq) + 0.5f * dot;
                    }
                }
        MEMFENCE;
    }

    // final flush: tile 7's chunks
    {
        const int base = (bb + 56) * BM;
#pragma unroll
        for (int c = 0; c < 4; ++c) STORE_CHUNK(c, base);
    }
}

// Fallback if workspace is too small: fully naive f32 (correct, slow).
__global__ void naive_kernel(const float* __restrict__ a,
                             const float* __restrict__ b,
                             float* __restrict__ out) {
    const size_t idx = (size_t)blockIdx.x * 256 + threadIdx.x;
    const int i = (int)(idx >> 13);
    const int j = (int)(idx & 8191);
    float dot = 0.f, naa = 0.f, nbb = 0.f;
    for (int k = 0; k < DIM; ++k) {
        const float x = a[(size_t)i * DIM + k];
        const float y = b[(size_t)j * DIM + k];
        dot += x * y; naa += x * x; nbb += y * y;
    }
    const float sq = naa + nbb - 2.0f * dot;
    out[idx] = 0.5f * __expf(-sq) + 0.5f * dot;
}

extern "C" void kernel_launch(void* const* d_in, const int* in_sizes, int n_in,
                              void* d_out, int out_size, void* d_ws, size_t ws_size,
                              hipStream_t stream) {
    const float* a = (const float*)d_in[0];
    const float* b = (const float*)d_in[1];
    // d_in[2]=Wq, d_in[3]=Wk unused: softmax over a 1x1 score == 1 exactly,
    // so attn_sim == a.b and the projections cancel.
    float* out = (float*)d_out;

    const size_t bf_bytes = (size_t)NR * DIM * sizeof(unsigned short);
    const size_t nrm_bytes = (size_t)NR * sizeof(float);
    const size_t need = 2 * bf_bytes + 2 * nrm_bytes;

    if (ws_size >= need) {
        unsigned short* aBf = (unsigned short*)d_ws;
        unsigned short* bBf = (unsigned short*)((char*)d_ws + bf_bytes);
        float* na = (float*)((char*)d_ws + 2 * bf_bytes);
        float* nb = (float*)((char*)d_ws + 2 * bf_bytes + nrm_bytes);

        prep_kernel<<<4096, 256, 0, stream>>>(a, b, aBf, bBf, na, nb);
        gemm_kernel<<<GRID, 256, 0, stream>>>(aBf, bBf, na, nb, out);
    } else {
        naive_kernel<<<((size_t)NR * NR) / 256, 256, 0, stream>>>(a, b, out);
    }
}